// Round 1
// baseline (64.300 us; speedup 1.0000x reference)
//
#include <hip/hip_runtime.h>

// CFNet filter-adaptive convolution (customized FAC), fp32.
// feat_in: (8,3,512,512)  kernel: (8,100,256,256)  out: (8,3,256,256)
//
// Derived index mapping (see analysis): for output (n,c2,h,w), tap t:
//   tb=t/25, u=t%25, j=u/5, i=u%5, (d,c)=table[tb][c2]
//   feat element = fp_padded[n, c, 2h+(w>>7)+i, 4*(w&127)+d+j]   (pad=2 replicate)
//   kernel tap   = kernel[n, (t%10)*10 + t/10, h, w]

#define H2 512
#define W2 512
#define HH 256
#define WW 256
#define PY 516   // 512 + 2*pad
#define PX 520   // 512 + 2*pad padded to float4-friendly width (reads reach col 519)

// ---------------- pad pass: replicate-pad feat into d_ws ----------------
__global__ __launch_bounds__(256) void pad_feat(const float* __restrict__ feat,
                                                float* __restrict__ fp) {
    int idx = blockIdx.x * 256 + threadIdx.x;   // total = 24*PY*PX, grid exact
    int x  = idx % PX;
    int r  = idx / PX;
    int y  = r % PY;
    int nc = r / PY;
    int sx = min(max(x - 2, 0), W2 - 1);
    int sy = min(max(y - 2, 0), H2 - 1);
    fp[idx] = feat[((size_t)nc * H2 + sy) * W2 + sx];
}

// ---------------- main FAC kernel ----------------
// PADDED=true : src = padded feat (PYxPX rows), aligned float4 loads, no clamps
// PADDED=false: src = raw feat, clamped scalar gathers (ws-too-small fallback)
template <bool PADDED>
__global__ __launch_bounds__(256) void fac_main(const float* __restrict__ src,
                                                const float* __restrict__ kern,
                                                float* __restrict__ out) {
    int tid = blockIdx.x * 256 + threadIdx.x;
    int w = tid & (WW - 1);
    int h = (tid >> 8) & (HH - 1);
    int n = tid >> 16;

    int hi = w >> 7;             // row-half select from the reshape wraparound
    int xb = (w & 127) << 2;     // x2 base = 4*(w&127), float4 aligned
    int y2 = 2 * h + hi;

    const float* kp = kern + (size_t)n * 100 * (HH * WW) + (size_t)h * WW + w;

    // (d,c) per (tb, c2) — compile-time folded under full unroll
    const int d_tab[4][3] = {{0,1,2},{0,1,3},{0,2,3},{1,2,3}};
    const int c_tab[4][3] = {{0,1,2},{1,2,0},{2,0,1},{0,1,2}};

    float acc0 = 0.f, acc1 = 0.f, acc2 = 0.f;

#pragma unroll
    for (int i = 0; i < 5; ++i) {
        float fr[3][12];
#pragma unroll
        for (int c = 0; c < 3; ++c) {
            if (PADDED) {
                const float* rp = src + (((size_t)n * 3 + c) * PY + (y2 + i)) * PX + xb;
                float4 q0 = *(const float4*)(rp);
                float4 q1 = *(const float4*)(rp + 4);
                float4 q2 = *(const float4*)(rp + 8);
                fr[c][0] = q0.x; fr[c][1]  = q0.y; fr[c][2]  = q0.z; fr[c][3]  = q0.w;
                fr[c][4] = q1.x; fr[c][5]  = q1.y; fr[c][6]  = q1.z; fr[c][7]  = q1.w;
                fr[c][8] = q2.x; fr[c][9]  = q2.y; fr[c][10] = q2.z; fr[c][11] = q2.w;
            } else {
                int sy = min(max(y2 + i - 2, 0), H2 - 1);
                const float* rp = src + (((size_t)n * 3 + c) * H2 + sy) * W2;
#pragma unroll
                for (int s = 0; s < 9; ++s) {
                    int sx = min(max(xb + s - 2, 0), W2 - 1);
                    fr[c][s] = rp[sx];
                }
                fr[c][9] = fr[c][10] = fr[c][11] = 0.f;
            }
        }
#pragma unroll
        for (int j = 0; j < 5; ++j) {
#pragma unroll
            for (int tb = 0; tb < 4; ++tb) {
                int t  = tb * 25 + j * 5 + i;
                int kc = (t % 10) * 10 + (t / 10);   // transposed 10x10 tap grid
                float kv = kp[(size_t)kc * (HH * WW)];
                acc0 += kv * fr[c_tab[tb][0]][d_tab[tb][0] + j];
                acc1 += kv * fr[c_tab[tb][1]][d_tab[tb][1] + j];
                acc2 += kv * fr[c_tab[tb][2]][d_tab[tb][2] + j];
            }
        }
    }

    size_t ob = (size_t)n * 3 * (HH * WW) + (size_t)h * WW + w;
    out[ob]                = acc0;
    out[ob + HH * WW]      = acc1;
    out[ob + 2 * HH * WW]  = acc2;
}

extern "C" void kernel_launch(void* const* d_in, const int* in_sizes, int n_in,
                              void* d_out, int out_size, void* d_ws, size_t ws_size,
                              hipStream_t stream) {
    const float* feat = (const float*)d_in[0];   // 8*3*512*512
    const float* kern = (const float*)d_in[1];   // 8*100*256*256
    float* out = (float*)d_out;                  // 8*3*256*256

    const size_t padElems = (size_t)24 * PY * PX;           // 6,439,680
    const size_t padBytes = padElems * sizeof(float);       // ~25.8 MB

    const int mainBlocks = (8 * HH * WW) / 256;             // 2048

    if (ws_size >= padBytes) {
        float* fp = (float*)d_ws;
        pad_feat<<<(int)(padElems / 256), 256, 0, stream>>>(feat, fp);
        fac_main<true><<<mainBlocks, 256, 0, stream>>>(fp, kern, out);
    } else {
        fac_main<false><<<mainBlocks, 256, 0, stream>>>(feat, kern, out);
    }
}

// Round 2
// 64.035 us; speedup vs baseline: 1.0041x; 1.0041x over previous
//
#include <hip/hip_runtime.h>

// CFNet filter-adaptive convolution (customized FAC), fp32.
// feat_in: (8,3,512,512)  kernel: (8,100,256,256)  out: (8,3,256,256)
//
// Index mapping: for output (n,c2,h,w), tap t = 25*tb + 5*j + i:
//   (d,c) = table[tb][c2]
//   feat element = fp_padded[n, c, 2h+(w>>7)+i, 4*(w&127)+d+j]   (pad=2 replicate)
//   kernel tap   = kernel[n, (t%10)*10 + t/10, h, w]
//                = kernel[n, 10*i + 50*(a&1) + (a>>1), h, w]  with a = 5*tb+j
// so with i a RUNTIME loop var, all per-tap offsets are compile-time consts.

#define H2 512
#define W2 512
#define HH 256
#define WW 256
#define PY 516   // 512 + 2*pad
#define PX 520   // 512 + 2*pad, padded so each 8-float segment is float4-aligned

// ---------------- pad pass: replicate-pad feat into d_ws ----------------
__global__ __launch_bounds__(256) void pad_feat(const float* __restrict__ feat,
                                                float* __restrict__ fp) {
    int idx = blockIdx.x * 256 + threadIdx.x;   // total = 24*PY*PX, grid exact
    int x  = idx % PX;
    int r  = idx / PX;
    int y  = r % PY;
    int nc = r / PY;
    int sx = min(max(x - 2, 0), W2 - 1);
    int sy = min(max(y - 2, 0), H2 - 1);
    fp[idx] = feat[((size_t)nc * H2 + sy) * W2 + sx];
}

// ---------------- main FAC kernel ----------------
template <bool PADDED>
__global__ __launch_bounds__(256) void fac_main(const float* __restrict__ src,
                                                const float* __restrict__ kern,
                                                float* __restrict__ out) {
    int tid = blockIdx.x * 256 + threadIdx.x;
    int w = tid & (WW - 1);
    int h = (tid >> 8) & (HH - 1);
    int n = tid >> 16;

    int hi = w >> 7;             // row-half select from the reshape wraparound
    int xb = (w & 127) << 2;     // x2 base = 4*(w&127); float4-aligned padded col
    int y2 = 2 * h + hi;

    const float* kp = kern + (size_t)n * 100 * (HH * WW) + (size_t)h * WW + w;

    // (d,c) per (tb, c2) — compile-time folded (tb/j loops fully unrolled)
    const int d_tab[4][3] = {{0,1,2},{0,1,3},{0,2,3},{1,2,3}};
    const int c_tab[4][3] = {{0,1,2},{1,2,0},{2,0,1},{0,1,2}};

    float acc0 = 0.f, acc1 = 0.f, acc2 = 0.f;

    // base pointer of row y2, col xb, channel 0 (padded layout)
    const float* rbase = PADDED
        ? src + ((size_t)n * 3 * PY + y2) * PX + xb
        : src;                                  // unused directly in fallback

#pragma unroll 1
    for (int i = 0; i < 5; ++i) {
        float fr[3][8];
        if (PADDED) {
            const float* r0 = rbase + (size_t)i * PX;
#pragma unroll
            for (int c = 0; c < 3; ++c) {
                float4 q0 = *(const float4*)(r0 + (size_t)c * (PY * PX));
                float4 q1 = *(const float4*)(r0 + (size_t)c * (PY * PX) + 4);
                fr[c][0] = q0.x; fr[c][1] = q0.y; fr[c][2] = q0.z; fr[c][3] = q0.w;
                fr[c][4] = q1.x; fr[c][5] = q1.y; fr[c][6] = q1.z; fr[c][7] = q1.w;
            }
        } else {
            int sy = min(max(y2 + i - 2, 0), H2 - 1);
#pragma unroll
            for (int c = 0; c < 3; ++c) {
                const float* rp = src + (((size_t)n * 3 + c) * H2 + sy) * W2;
#pragma unroll
                for (int s = 0; s < 8; ++s) {
                    int sx = min(max(xb + s - 2, 0), W2 - 1);
                    fr[c][s] = rp[sx];
                }
            }
        }

        const float* kpi = kp + (size_t)i * 10 * (HH * WW);
#pragma unroll
        for (int tb = 0; tb < 4; ++tb) {
#pragma unroll
            for (int j = 0; j < 5; ++j) {
                const int a5 = 5 * tb + j;                       // compile-time
                const int kc = (a5 & 1) * 50 + (a5 >> 1);        // + 10*i via kpi
                float kv = kpi[(size_t)kc * (HH * WW)];
                acc0 += kv * fr[c_tab[tb][0]][d_tab[tb][0] + j];
                acc1 += kv * fr[c_tab[tb][1]][d_tab[tb][1] + j];
                acc2 += kv * fr[c_tab[tb][2]][d_tab[tb][2] + j];
            }
        }
    }

    size_t ob = (size_t)n * 3 * (HH * WW) + (size_t)h * WW + w;
    out[ob]               = acc0;
    out[ob + HH * WW]     = acc1;
    out[ob + 2 * HH * WW] = acc2;
}

extern "C" void kernel_launch(void* const* d_in, const int* in_sizes, int n_in,
                              void* d_out, int out_size, void* d_ws, size_t ws_size,
                              hipStream_t stream) {
    const float* feat = (const float*)d_in[0];   // 8*3*512*512
    const float* kern = (const float*)d_in[1];   // 8*100*256*256
    float* out = (float*)d_out;                  // 8*3*256*256

    const size_t padElems = (size_t)24 * PY * PX;           // 6,439,680
    const size_t padBytes = padElems * sizeof(float);       // ~25.8 MB

    const int mainBlocks = (8 * HH * WW) / 256;             // 2048

    if (ws_size >= padBytes) {
        float* fp = (float*)d_ws;
        pad_feat<<<(int)(padElems / 256), 256, 0, stream>>>(feat, fp);
        fac_main<true><<<mainBlocks, 256, 0, stream>>>(fp, kern, out);
    } else {
        fac_main<false><<<mainBlocks, 256, 0, stream>>>(feat, kern, out);
    }
}

// Round 4
// 51.292 us; speedup vs baseline: 1.2536x; 1.2484x over previous
//
#include <hip/hip_runtime.h>

// CFNet filter-adaptive convolution (customized FAC), fp32 — fully fused.
// feat_in: (8,3,512,512)  kernel: (8,100,256,256)  out: (8,3,256,256)
//
// Index mapping: for output (n,c2,h,w), tap t = 25*tb + 5*j + i:
//   (d,c) = table[tb][c2]
//   feat element = feat[n, c, clamp(2h+(w>>7)+i-2), clamp(4*(w&127)+d+j-2)]
//   kernel tap   = kernel[n, 10*i + 50*(a&1) + (a>>1), h, w],  a = 5*tb+j
//
// 2 pixels (w, w+1) per thread -> kern taps load as 8-byte vectors
// (512 B per wave-request, halves VMEM instr count vs scalar dword).
// Replicate padding handled in-kernel: y via clamped row address, x via
// compile-time-indexed selects for the two edge lane classes.

#define HH 256
#define WW 256
#define H2 512
#define W2 512
#define KPLANE (HH * WW)   // 65536
#define KP2 (KPLANE / 2)   // 32768 float-pairs per kernel plane

typedef float f32x2 __attribute__((ext_vector_type(2)));

__global__ __launch_bounds__(256, 4) void fac_fused(const float* __restrict__ feat,
                                                    const float* __restrict__ kern,
                                                    float* __restrict__ out) {
    int t  = blockIdx.x * 256 + threadIdx.x;   // 262144 threads total
    int wp = t & 127;            // pixel pair index: w = 2*wp
    int h  = (t >> 7) & 255;
    int n  = t >> 15;
    int w  = wp << 1;

    int hi = w >> 7;             // wave-uniform (lanes span 64 consecutive wp)
    int xb = (w & 127) << 2;     // 0,8,...,504
    int y2 = 2 * h + hi;

    bool e0 = (xb == 0);         // left-edge lane class
    bool e1 = (xb == 504);       // right-edge lane class
    int wbase = e0 ? 0 : (e1 ? 496 : (xb - 4));   // 16-float window base, 16B-aligned

    const f32x2* kp2 = (const f32x2*)(kern + (size_t)n * 100 * KPLANE +
                                      (size_t)h * WW + w);

    const int d_tab[4][3] = {{0,1,2},{0,1,3},{0,2,3},{1,2,3}};
    const int c_tab[4][3] = {{0,1,2},{1,2,0},{2,0,1},{0,1,2}};

    float a0x = 0.f, a0y = 0.f, a1x = 0.f, a1y = 0.f, a2x = 0.f, a2y = 0.f;

#pragma unroll 1
    for (int i = 0; i < 5; ++i) {
        int sy = min(max(y2 + i - 2, 0), H2 - 1);   // replicate pad in y

        // 16-float window per channel; extract 12 taps with compile-time idx
        float fr[3][12];
#pragma unroll
        for (int c = 0; c < 3; ++c) {
            const float* rp = feat + ((size_t)(n * 3 + c) * H2 + sy) * W2 + wbase;
            float4 q0 = *(const float4*)(rp);
            float4 q1 = *(const float4*)(rp + 4);
            float4 q2 = *(const float4*)(rp + 8);
            float4 q3 = *(const float4*)(rp + 12);
            float win[16] = {q0.x, q0.y, q0.z, q0.w, q1.x, q1.y, q1.z, q1.w,
                             q2.x, q2.y, q2.z, q2.w, q3.x, q3.y, q3.z, q3.w};
#pragma unroll
            for (int s = 0; s < 12; ++s) {
                const int i_in = s + 2;                       // interior: col xb-2+s
                const int i_e0 = (s - 2) < 0 ? 0 : (s - 2);   // xb==0: clamp left
                const int i_e1 = (s + 6) > 15 ? 15 : (s + 6); // xb==504: clamp right
                fr[c][s] = e0 ? win[i_e0] : (e1 ? win[i_e1] : win[i_in]);
            }
        }

        const f32x2* kpi = kp2 + (size_t)i * 10 * KP2;
#pragma unroll
        for (int tb = 0; tb < 4; ++tb) {
#pragma unroll
            for (int j = 0; j < 5; ++j) {
                const int a5 = 5 * tb + j;                    // compile-time
                const int kc = (a5 & 1) * 50 + (a5 >> 1);     // +10*i via kpi
                f32x2 kv = __builtin_nontemporal_load(kpi + (size_t)kc * KP2);

                const int d0 = d_tab[tb][0], c0 = c_tab[tb][0];
                const int d1 = d_tab[tb][1], c1 = c_tab[tb][1];
                const int d2 = d_tab[tb][2], c2 = c_tab[tb][2];
                a0x += kv.x * fr[c0][d0 + j];
                a0y += kv.y * fr[c0][d0 + j + 4];
                a1x += kv.x * fr[c1][d1 + j];
                a1y += kv.y * fr[c1][d1 + j + 4];
                a2x += kv.x * fr[c2][d2 + j];
                a2y += kv.y * fr[c2][d2 + j + 4];
            }
        }
    }

    float* op = out + (size_t)n * 3 * KPLANE + (size_t)h * WW + w;
    *(float2*)(op)              = make_float2(a0x, a0y);
    *(float2*)(op + KPLANE)     = make_float2(a1x, a1y);
    *(float2*)(op + 2 * KPLANE) = make_float2(a2x, a2y);
}

extern "C" void kernel_launch(void* const* d_in, const int* in_sizes, int n_in,
                              void* d_out, int out_size, void* d_ws, size_t ws_size,
                              hipStream_t stream) {
    const float* feat = (const float*)d_in[0];   // 8*3*512*512
    const float* kern = (const float*)d_in[1];   // 8*100*256*256
    float* out = (float*)d_out;                  // 8*3*256*256

    // 262144 threads, 2 pixels each = 524288 outputs/channel-triple
    fac_fused<<<1024, 256, 0, stream>>>(feat, kern, out);
}

// Round 5
// 45.050 us; speedup vs baseline: 1.4273x; 1.1386x over previous
//
#include <hip/hip_runtime.h>

// CFNet filter-adaptive convolution (customized FAC), fp32 — fully fused, 4 px/thread.
// feat_in: (8,3,512,512)  kernel: (8,100,256,256)  out: (8,3,256,256)
//
// Index mapping: for output (n,c2,h,w), tap t = 25*tb + 5*j + i:
//   (d,c) = table[tb][c2]
//   feat element = feat[n, c, clamp(2h+(w>>7)+i-2), clamp(4*(w&127)+d+j-2)]
//   kernel tap   = kernel[n, 10*i + 50*(a&1) + (a>>1), h, w],  a = 5*tb+j
//
// 4 pixels (w..w+3) per thread -> every kern tap is ONE float4 load
// (16 B/lane, 1 KB/wave-instruction = the measured-6.3TB/s copy pattern).
// Pixel p uses feat window offset o = 4p + d + j  in [0,19]; the 24-float
// aligned window (6 float4) covers all four pixels' taps. Replicate padding:
// y via clamped row address, x via compile-time-indexed selects for the two
// edge lane classes (xb==0, xb==496).

#define HH 256
#define WW 256
#define H2 512
#define W2 512
#define KPLANE (HH * WW)   // 65536
#define KP4 (KPLANE / 4)   // 16384 float4 per kernel plane

typedef float f32x4_t __attribute__((ext_vector_type(4)));

__global__ __launch_bounds__(256, 2) void fac_fused4(const float* __restrict__ feat,
                                                     const float* __restrict__ kern,
                                                     float* __restrict__ out) {
    int t  = blockIdx.x * 256 + threadIdx.x;   // 131072 threads total
    int qp = t & 63;             // pixel-quad index: w = 4*qp
    int h  = (t >> 6) & 255;
    int n  = t >> 14;
    int w  = qp << 2;

    int hi = (qp >> 5) & 1;      // = w>>7; row-half select from reshape wrap
    int xb = (qp & 31) << 4;     // = 4*(w&127): 0,16,...,496
    int y2 = 2 * h + hi;

    bool e0 = (qp & 31) == 0;    // left-edge lane class  (xb==0)
    bool e1 = (qp & 31) == 31;   // right-edge lane class (xb==496)
    int wbase = e0 ? 0 : (e1 ? 488 : (xb - 4));   // 24-float window base, 16B-aligned

    const f32x4_t* kp4 = (const f32x4_t*)(kern + (size_t)n * 100 * KPLANE +
                                          (size_t)h * WW + w);

    const int d_tab[4][3] = {{0,1,2},{0,1,3},{0,2,3},{1,2,3}};
    const int c_tab[4][3] = {{0,1,2},{1,2,0},{2,0,1},{0,1,2}};

    float acc[3][4] = {};

#pragma unroll 1
    for (int i = 0; i < 5; ++i) {
        int sy = min(max(y2 + i - 2, 0), H2 - 1);   // replicate pad in y

        // 24-float window per channel; 20 taps extracted w/ compile-time idx
        float fr[3][20];
#pragma unroll
        for (int c = 0; c < 3; ++c) {
            const float* rp = feat + ((size_t)(n * 3 + c) * H2 + sy) * W2 + wbase;
            float4 q0 = *(const float4*)(rp);
            float4 q1 = *(const float4*)(rp + 4);
            float4 q2 = *(const float4*)(rp + 8);
            float4 q3 = *(const float4*)(rp + 12);
            float4 q4 = *(const float4*)(rp + 16);
            float4 q5 = *(const float4*)(rp + 20);
            float win[24] = {q0.x, q0.y, q0.z, q0.w, q1.x, q1.y, q1.z, q1.w,
                             q2.x, q2.y, q2.z, q2.w, q3.x, q3.y, q3.z, q3.w,
                             q4.x, q4.y, q4.z, q4.w, q5.x, q5.y, q5.z, q5.w};
#pragma unroll
            for (int o = 0; o < 20; ++o) {
                // col = xb + o - 2 (clamped). win base: interior xb-4, e0 0, e1 488
                const int i_in = o + 2;
                const int i_e0 = (o - 2) < 0 ? 0 : (o - 2);
                const int i_e1 = (o + 6) > 23 ? 23 : (o + 6);
                fr[c][o] = e0 ? win[i_e0] : (e1 ? win[i_e1] : win[i_in]);
            }
        }

        const f32x4_t* kpi = kp4 + (size_t)i * 10 * KP4;
#pragma unroll
        for (int tb = 0; tb < 4; ++tb) {
#pragma unroll
            for (int j = 0; j < 5; ++j) {
                const int a5 = 5 * tb + j;                    // compile-time
                const int kc = (a5 & 1) * 50 + (a5 >> 1);     // +10*i via kpi
                f32x4_t kv = __builtin_nontemporal_load(kpi + (size_t)kc * KP4);

                const int d0 = d_tab[tb][0], c0 = c_tab[tb][0];
                const int d1 = d_tab[tb][1], c1 = c_tab[tb][1];
                const int d2 = d_tab[tb][2], c2 = c_tab[tb][2];
#pragma unroll
                for (int p = 0; p < 4; ++p) {
                    acc[0][p] += kv[p] * fr[c0][d0 + j + 4 * p];
                    acc[1][p] += kv[p] * fr[c1][d1 + j + 4 * p];
                    acc[2][p] += kv[p] * fr[c2][d2 + j + 4 * p];
                }
            }
        }
    }

    float* op = out + (size_t)n * 3 * KPLANE + (size_t)h * WW + w;
#pragma unroll
    for (int c = 0; c < 3; ++c) {
        *(float4*)(op + (size_t)c * KPLANE) =
            make_float4(acc[c][0], acc[c][1], acc[c][2], acc[c][3]);
    }
}

extern "C" void kernel_launch(void* const* d_in, const int* in_sizes, int n_in,
                              void* d_out, int out_size, void* d_ws, size_t ws_size,
                              hipStream_t stream) {
    const float* feat = (const float*)d_in[0];   // 8*3*512*512
    const float* kern = (const float*)d_in[1];   // 8*100*256*256
    float* out = (float*)d_out;                  // 8*3*256*256

    // 131072 threads, 4 pixels each; 512 blocks
    fac_fused4<<<512, 256, 0, stream>>>(feat, kern, out);
}